// Round 13
// baseline (823.190 us; speedup 1.0000x reference)
//
#include <hip/hip_runtime.h>
#include <hip/hip_bf16.h>
#include <math.h>

#define VOCAB 50257
#define VPAD  50432          // VOCAB padded to multiple of 256
#define EMB   1024
#define NROWS 4096

#define BM 256
#define BN 256
#define BK 64
#define NKT (EMB / BK)       // 16
#define NMT (NROWS / BM)     // 16
#define NT  (VPAD / BN)      // 197
#define NWG (NMT * NT)       // 3152 (divisible by 8)

typedef __attribute__((ext_vector_type(4))) float  f32x4;
typedef __attribute__((ext_vector_type(4), aligned(4))) float f32x4u;
typedef __attribute__((ext_vector_type(4))) __bf16 bf16x4;
typedef __attribute__((ext_vector_type(8))) __bf16 bf16x8;

#define FENCE asm volatile("" ::: "memory")
#define BARRIER do { FENCE; __builtin_amdgcn_s_barrier(); FENCE; } while (0)

// ---------------------------------------------------------------------------
// fp32 -> bf16 convert (pads tail with zeros). n_src, n_dst multiples of 8.
// ---------------------------------------------------------------------------
__global__ __launch_bounds__(256)
void cvt_bf16(const float* __restrict__ src, __bf16* __restrict__ dst,
              long n_src, long n_dst) {
    long i = ((long)blockIdx.x * 256 + threadIdx.x) * 8;
    if (i >= n_dst) return;
    bf16x8 o;
    if (i < n_src) {
        f32x4 a = *(const f32x4*)(src + i);
        f32x4 b = *(const f32x4*)(src + i + 4);
        #pragma unroll
        for (int e = 0; e < 4; ++e) {
            o[e]     = (__bf16)a[e];
            o[4 + e] = (__bf16)b[e];
        }
    } else {
        #pragma unroll
        for (int e = 0; e < 8; ++e) o[e] = (__bf16)0.0f;
    }
    *(bf16x8*)(dst + i) = o;
}

// ---------------------------------------------------------------------------
// 256x256-tile bf16 GEMM, death-aligned 4-phase schedule:
//   LDS per buf: A[mh][128r][64k] (2x16KB) | B[ks][256r][32k] (2x16KB).
//   Phase p of tile t: {stage one unit per schedule; ds_read quadrant;
//   BARRIER; MFMA16; BARRIER}. Units staged into regions that died at an
//   earlier phase (B0 dead after ph0, A0 after ph2, B1/A1 after ph3), giving
//   issue->wait = 2..5 phases with ONE boundary vmcnt(4) per K-tile.
//   Stage calendar: ph0: B1(t+1)->c^1 | ph1: A1(t+1)->c^1 |
//                   ph2: B0(t+2)->c   | ph3: A0(t+2)->c, then vmcnt(4).
// Fused sum-exp epilogue; Lb stores first, exp/reduce drain under them.
// ---------------------------------------------------------------------------
template <bool LB_OUT>
__global__ __launch_bounds__(512, 2)
void gemm_fused(const __bf16* __restrict__ A, const __bf16* __restrict__ B,
                float* __restrict__ C, __bf16* __restrict__ Lb,
                float* __restrict__ pbuf) {
    __shared__ alignas(16) __bf16 S[65536];   // 128 KiB

    const int tid  = threadIdx.x;
    const int lane = tid & 63;
    const int wave = tid >> 6;
    const int wm   = (wave >> 2) * 128;       // 2 M-halves
    const int wn   = (wave & 3) * 64;         // 4 N-quarters
    const int frow = lane & 15;
    const int hi   = lane >> 4;

    // bijective XCD swizzle: NWG = 3152, 3152/8 = 394
    const int b  = blockIdx.x;
    const int lg = (b & 7) * (NWG / 8) + (b >> 3);
    const int mt = lg & (NMT - 1);            // m-fastest: 16 blocks share W panel
    const int nt = lg >> 4;
    const int mtB = mt * BM, ntB = nt * BN;

    f32x4 acc[8][4];
    const f32x4 vzero = {0.f, 0.f, 0.f, 0.f};
    #pragma unroll
    for (int m = 0; m < 8; ++m)
        #pragma unroll
        for (int n = 0; n < 4; ++n) acc[m][n] = vzero;

#define GLOAD(gp, dp)                                                         \
    __builtin_amdgcn_global_load_lds(                                         \
        (const __attribute__((address_space(1))) void*)(gp),                 \
        (__attribute__((address_space(3))) void*)(dp), 16, 0, 0)

    // A unit (mh): 16KB, [128 lrow][64k]; lrow -> global row gr.
    // source k-slot pre-swizzled with (lrow&7) to match read XOR.
#define STAGE_A(bc, kt, mh) do {                                              \
        int n_ = tid, lr_ = n_ >> 3;                                          \
        int gr_ = (lr_ & 63) + (mh) * 64 + ((lr_ >> 6) << 7);                 \
        GLOAD(A + (size_t)(mtB + gr_) * EMB + (kt) * BK                       \
                + (((n_ & 7) ^ (lr_ & 7)) * 8),                               \
              &S[(bc) * 32768 + (mh) * 8192 + wave * 512]);                   \
        n_ = tid + 512; lr_ = n_ >> 3;                                        \
        gr_ = (lr_ & 63) + (mh) * 64 + ((lr_ >> 6) << 7);                     \
        GLOAD(A + (size_t)(mtB + gr_) * EMB + (kt) * BK                       \
                + (((n_ & 7) ^ (lr_ & 7)) * 8),                               \
              &S[(bc) * 32768 + (mh) * 8192 + 4096 + wave * 512]);            \
    } while (0)

    // B unit (ks): 16KB, [256 row][32k]; source pre-swizzled with ((rb>>1)&3).
#define STAGE_B(bc, kt, ks) do {                                              \
        int n_ = tid, rb_ = n_ >> 2;                                          \
        GLOAD(B + (size_t)(ntB + rb_) * EMB + (kt) * BK + (ks) * 32           \
                + (((n_ & 3) ^ ((rb_ >> 1) & 3)) * 8),                        \
              &S[(bc) * 32768 + 16384 + (ks) * 8192 + wave * 512]);           \
        n_ = tid + 512; rb_ = n_ >> 2;                                        \
        GLOAD(B + (size_t)(ntB + rb_) * EMB + (kt) * BK + (ks) * 32           \
                + (((n_ & 3) ^ ((rb_ >> 1) & 3)) * 8),                        \
              &S[(bc) * 32768 + 16384 + (ks) * 8192 + 4096 + wave * 512]);    \
    } while (0)

#define LDA_F(bc, mh, ks) { _Pragma("unroll")                                 \
    for (int i_ = 0; i_ < 4; ++i_) {                                          \
        const int lrow_ = (i_ * 16 + frow) + ((wm >> 7) << 6);                \
        af[i_] = *(const bf16x8*)&S[(bc) * 32768 + (mh) * 8192               \
            + lrow_ * 64 + ((((ks) * 4 + hi) ^ (lrow_ & 7)) * 8)]; } }

#define LDB_F(bc, ks) { _Pragma("unroll")                                     \
    for (int n_ = 0; n_ < 4; ++n_) {                                          \
        const int rb_ = wn + n_ * 16 + frow;                                  \
        bfr[n_] = *(const bf16x8*)&S[(bc) * 32768 + 16384 + (ks) * 8192      \
            + rb_ * 32 + (((hi ^ ((rb_ >> 1) & 3))) * 8)]; } }

#define MFMA16(mh)                                                            \
    __builtin_amdgcn_s_setprio(1);                                            \
    _Pragma("unroll") for (int i_ = 0; i_ < 4; ++i_)                          \
        _Pragma("unroll") for (int n_ = 0; n_ < 4; ++n_)                      \
            acc[(mh) * 4 + i_][n_] = __builtin_amdgcn_mfma_f32_16x16x32_bf16( \
                af[i_], bfr[n_], acc[(mh) * 4 + i_][n_], 0, 0, 0);            \
    __builtin_amdgcn_s_setprio(0);

    bf16x8 af[4], bfr[4];

    // prologue: tile0 complete -> buf0; B0,A0 of tile1 -> buf1 (stay in flight
    // rules emulated: vmcnt(4) = tile0 landed, tile1's 2 units flying)
    STAGE_B(0, 0, 0); STAGE_A(0, 0, 0); STAGE_B(0, 0, 1); STAGE_A(0, 0, 1);
    STAGE_B(1, 1, 0); STAGE_A(1, 1, 0);
    asm volatile("s_waitcnt vmcnt(4)" ::: "memory");
    BARRIER;

    for (int t = 0; t < NKT; ++t) {
        const int c   = t & 1;
        const bool p1 = (t + 1 < NKT);
        const bool p2 = (t + 2 < NKT);

        // ---- phase 0: (mh0, ks0) ----
        LDB_F(c, 0); LDA_F(c, 0, 0);
        if (p1) STAGE_B(c ^ 1, t + 1, 1);        // B1(t+1): region dead since t-1 ph2
        BARRIER;
        MFMA16(0);
        BARRIER;
        // ---- phase 1: (mh1, ks0) ----           B-ks0 regs persist
        LDA_F(c, 1, 0);
        if (p1) STAGE_A(c ^ 1, t + 1, 1);        // A1(t+1): dead since t-1 ph3
        BARRIER;
        MFMA16(1);
        BARRIER;
        // ---- phase 2: (mh0, ks1) ----
        LDB_F(c, 1); LDA_F(c, 0, 1);
        if (p2) STAGE_B(c, t + 2, 0);            // B0(t+2) -> buf c B0 (dead after ph0)
        BARRIER;
        MFMA16(0);
        BARRIER;
        // ---- phase 3: (mh1, ks1) ----
        LDA_F(c, 1, 1);
        if (p2) STAGE_A(c, t + 2, 0);            // A0(t+2) -> buf c A0 (dead after ph2)
        if (p2)      asm volatile("s_waitcnt vmcnt(4)" ::: "memory"); // t+1 landed, 2 fly
        else if (p1) asm volatile("s_waitcnt vmcnt(0)" ::: "memory"); // drain for last tile
        BARRIER;
        MFMA16(1);
        BARRIER;
    }
#undef STAGE_A
#undef STAGE_B
#undef GLOAD

    // ---------------- fused epilogue (stores first, sums under them) ------
    __syncthreads();                      // staging LDS reusable
    const bool edge = (ntB + BN > VOCAB); // only last nt tile

    if (LB_OUT) {
        #pragma unroll
        for (int m = 0; m < 8; ++m) {
            const size_t rbase = (size_t)(mtB + wm + m * 16 + hi * 4) * VPAD;
            #pragma unroll
            for (int n = 0; n < 4; ++n) {
                const size_t col = ntB + wn + n * 16 + frow;
                #pragma unroll
                for (int r = 0; r < 4; ++r)
                    Lb[rbase + (size_t)r * VPAD + col] = (__bf16)acc[m][n][r];
            }
        }
    } else {
        #pragma unroll
        for (int m = 0; m < 8; ++m) {
            const size_t rbase = (size_t)(mtB + wm + m * 16 + hi * 4) * VOCAB;
            #pragma unroll
            for (int n = 0; n < 4; ++n) {
                const int col = ntB + wn + n * 16 + frow;
                if (!edge || col < VOCAB) {
                    #pragma unroll
                    for (int r = 0; r < 4; ++r)
                        C[rbase + (size_t)r * VOCAB + col] = acc[m][n][r];
                }
            }
        }
    }

    // per-lane exp-sums -> LDS transpose buffer [256 rows][68] f32 (68 KB)
    float* ldsP = (float*)&S[0];
    const int lcid = (wave & 3) * 16 + frow;   // 0..63 column-group id
    #pragma unroll
    for (int m = 0; m < 8; ++m) {
        #pragma unroll
        for (int r = 0; r < 4; ++r) {
            float s = 0.0f;
            #pragma unroll
            for (int n = 0; n < 4; ++n) {
                if (!edge || (ntB + wn + n * 16 + frow) < VOCAB)
                    s += __expf(acc[m][n][r]);
            }
            ldsP[(wm + m * 16 + hi * 4 + r) * 68 + lcid] = s;
        }
    }
    __syncthreads();

    // reduce 64 partials per row -> pbuf[nt][global row]
    {
        const int rl = tid >> 1, hf = tid & 1;
        const float* q = ldsP + rl * 68 + hf * 32;
        float s = 0.0f;
        #pragma unroll
        for (int k = 0; k < 8; ++k) {
            f32x4 v = *(const f32x4*)(q + k * 4);
            s += v[0] + v[1] + v[2] + v[3];
        }
        s += __shfl_xor(s, 1);
        if (hf == 0) pbuf[(size_t)nt * NROWS + mtB + rl] = s;
    }
}

// ---------------------------------------------------------------------------
// reduce NT per-tile sumexp partials -> lse[row]; 64 rows per block
// ---------------------------------------------------------------------------
__global__ __launch_bounds__(256)
void lse_reduce(const float* __restrict__ pbuf, float* __restrict__ lse) {
    __shared__ float sl[4][64];
    const int r0 = blockIdx.x * 64;
    const int l  = threadIdx.x & 63;
    const int w  = threadIdx.x >> 6;
    float s = 0.0f;
    for (int t = w; t < NT; t += 4)
        s += pbuf[(size_t)t * NROWS + r0 + l];
    sl[w][l] = s;
    __syncthreads();
    if (threadIdx.x < 64)
        lse[r0 + l] = __logf(sl[0][l] + sl[1][l] + sl[2][l] + sl[3][l]);
}

// ---------------------------------------------------------------------------
// C[row][col] = (float)Lb[row][col] - lse[row]; 2 blocks per row (halves),
// nontemporal load/store (read-once / write-once data).
// ---------------------------------------------------------------------------
__global__ __launch_bounds__(256)
void expand_sub(const __bf16* __restrict__ Lb, const float* __restrict__ lse,
                float* __restrict__ C) {
    const int row  = blockIdx.x >> 1;
    const int half = blockIdx.x & 1;
    const float s = lse[row];
    const __bf16* src = Lb + (size_t)row * VPAD;
    float* dst = C + (size_t)row * VOCAB;
    // 50257 = 8*6282 + 1; half 0: chunks [0,3141), half 1: [3141,6282)
    const int i0 = half * 3141;
    const int i1 = i0 + 3141;
    for (int i = i0 + threadIdx.x; i < i1; i += 256) {
        bf16x8 v = __builtin_nontemporal_load((const bf16x8*)(src + i * 8));
        f32x4u a, b2;
        a[0] = (float)v[0] - s; a[1] = (float)v[1] - s;
        a[2] = (float)v[2] - s; a[3] = (float)v[3] - s;
        b2[0] = (float)v[4] - s; b2[1] = (float)v[5] - s;
        b2[2] = (float)v[6] - s; b2[3] = (float)v[7] - s;
        __builtin_nontemporal_store(a,  (f32x4u*)(dst + i * 8));
        __builtin_nontemporal_store(b2, (f32x4u*)(dst + i * 8 + 4));
    }
    if (half == 1 && threadIdx.x == 0)
        dst[50256] = (float)src[50256] - s;
}

// ---------------------------------------------------------------------------
// out[row][col] -= lse[row]; fallback when Lb doesn't fit
// ---------------------------------------------------------------------------
__global__ __launch_bounds__(256)
void sub_lse(float* __restrict__ C, const float* __restrict__ lse) {
    const int row = blockIdx.x;
    const float s = lse[row];
    float* p = C + (size_t)row * VOCAB;
    for (int i = threadIdx.x; i < 12564; i += 256) {
        f32x4u v = *(const f32x4u*)(p + 4 * i);
        v[0] -= s; v[1] -= s; v[2] -= s; v[3] -= s;
        *(f32x4u*)(p + 4 * i) = v;
    }
    if (threadIdx.x == 0) p[50256] -= s;
}

// ---------------------------------------------------------------------------
// fallback fp32-input GEMM (128x128, R1 structure) if ws too small
// ---------------------------------------------------------------------------
#define FBM 128
#define FBK 32
__device__ __forceinline__ int swz_idx(int row, int col) {
    int slot = (col >> 3) ^ ((row >> 1) & 3);
    return row * FBK + slot * 8 + (col & 7);
}

__global__ __launch_bounds__(256, 2)
void gemm_logits(const float* __restrict__ H, const float* __restrict__ W,
                 float* __restrict__ C) {
    __shared__ __bf16 ldsA[FBM * FBK];
    __shared__ __bf16 ldsB[FBM * FBK];

    const int tid  = threadIdx.x;
    const int lane = tid & 63;
    const int wave = tid >> 6;
    const int wm = (wave >> 1) * 64;
    const int wn = (wave & 1) * 64;
    const int mt = blockIdx.x;
    const int nt = blockIdx.y;
    const int srow = tid >> 1;
    const int scol = (tid & 1) * 16;
    const int brow_g = nt * FBM + srow;
    const bool bvalid = brow_g < VOCAB;
    const float* aptr = H + (size_t)(mt * FBM + srow) * EMB + scol;
    const float* bptr = W + (size_t)(bvalid ? brow_g : 0) * EMB + scol;

    f32x4 areg[4], breg[4];
    #pragma unroll
    for (int q = 0; q < 4; ++q) {
        areg[q] = *(const f32x4*)(aptr + q * 4);
        breg[q] = *(const f32x4*)(bptr + q * 4);
    }
    f32x4 acc[4][4];
    const f32x4 vzero = {0.f, 0.f, 0.f, 0.f};
    #pragma unroll
    for (int i = 0; i < 4; ++i)
        #pragma unroll
        for (int j = 0; j < 4; ++j) acc[i][j] = vzero;

    const int frow = lane & 15;
    const int kcol = (lane >> 4) * 8;

    for (int kt = 0; kt < EMB / FBK; ++kt) {
        __syncthreads();
        #pragma unroll
        for (int q = 0; q < 4; ++q) {
            const int col = scol + q * 4;
            bf16x4 av, bv;
            #pragma unroll
            for (int e = 0; e < 4; ++e) {
                av[e] = (__bf16)areg[q][e];
                bv[e] = bvalid ? (__bf16)breg[q][e] : (__bf16)0.0f;
            }
            *(bf16x4*)(&ldsA[swz_idx(srow, col)]) = av;
            *(bf16x4*)(&ldsB[swz_idx(srow, col)]) = bv;
        }
        __syncthreads();
        if (kt + 1 < EMB / FBK) {
            const int ko = (kt + 1) * FBK;
            #pragma unroll
            for (int q = 0; q < 4; ++q) {
                areg[q] = *(const f32x4*)(aptr + ko + q * 4);
                breg[q] = *(const f32x4*)(bptr + ko + q * 4);
            }
        }
        bf16x8 af[4], bfr[4];
        #pragma unroll
        for (int i = 0; i < 4; ++i) {
            af[i]  = *(const bf16x8*)(&ldsA[swz_idx(wm + i * 16 + frow, kcol)]);
            bfr[i] = *(const bf16x8*)(&ldsB[swz_idx(wn + i * 16 + frow, kcol)]);
        }
        #pragma unroll
        for (int i = 0; i < 4; ++i)
            #pragma unroll
            for (int j = 0; j < 4; ++j)
                acc[i][j] = __builtin_amdgcn_mfma_f32_16x16x32_bf16(
                    af[i], bfr[j], acc[i][j], 0, 0, 0);
    }

    const int crow = mt * FBM + wm + (lane >> 4) * 4;
    const int ccol = nt * FBM + wn + (lane & 15);
    #pragma unroll
    for (int i = 0; i < 4; ++i) {
        #pragma unroll
        for (int j = 0; j < 4; ++j) {
            const int col = ccol + j * 16;
            if (col < VOCAB) {
                #pragma unroll
                for (int r = 0; r < 4; ++r)
                    C[(size_t)(crow + i * 16 + r) * VOCAB + col] = acc[i][j][r];
            }
        }
    }
}

// ---------------------------------------------------------------------------
// fallback full row LSE
// ---------------------------------------------------------------------------
__global__ __launch_bounds__(256)
void row_lse(const float* __restrict__ C, float* __restrict__ lse) {
    const int row = blockIdx.x;
    const float* p = C + (size_t)row * VOCAB;

    float m = -INFINITY, l = 0.0f;
    for (int i = threadIdx.x; i < 12564; i += 256) {
        f32x4u v = *(const f32x4u*)(p + 4 * i);
        #pragma unroll
        for (int e = 0; e < 4; ++e) {
            const float x  = v[e];
            const float mn = fmaxf(m, x);
            l = l * __expf(m - mn) + __expf(x - mn);
            m = mn;
        }
    }
    if (threadIdx.x == 0) {
        const float x  = p[50256];
        const float mn = fmaxf(m, x);
        l = l * __expf(m - mn) + __expf(x - mn);
        m = mn;
    }
    #pragma unroll
    for (int off = 1; off < 64; off <<= 1) {
        const float mo = __shfl_xor(m, off);
        const float lo = __shfl_xor(l, off);
        const float mn = fmaxf(m, mo);
        l = l * __expf(m - mn) + lo * __expf(mo - mn);
        m = mn;
    }
    __shared__ float sm[4], sl[4];
    if ((threadIdx.x & 63) == 0) { sm[threadIdx.x >> 6] = m; sl[threadIdx.x >> 6] = l; }
    __syncthreads();
    if (threadIdx.x == 0) {
        m = sm[0]; l = sl[0];
        #pragma unroll
        for (int w = 1; w < 4; ++w) {
            const float mn = fmaxf(m, sm[w]);
            l = l * __expf(m - mn) + sl[w] * __expf(sm[w] - mn);
            m = mn;
        }
        lse[row] = m + __logf(l);
    }
}

// ---------------------------------------------------------------------------
extern "C" void kernel_launch(void* const* d_in, const int* in_sizes, int n_in,
                              void* d_out, int out_size, void* d_ws, size_t ws_size,
                              hipStream_t stream) {
    const float* H = (const float*)d_in[0];   // [4096][1024]
    const float* W = (const float*)d_in[1];   // [50257][1024]
    float* C   = (float*)d_out;               // [4096][50257]
    float* lse = (float*)d_ws;                // 4096 floats @ offset 0

    const long nH  = (long)NROWS * EMB;       // 4,194,304
    const long nW  = (long)VOCAB * EMB;       // 51,463,168
    const long nWp = (long)VPAD * EMB;        // 51,642,368

    // layout: lse | pbuf | Hb | Wb | Lb
    const size_t pb_off   = 16384;
    const size_t pb_bytes = (size_t)NT * NROWS * sizeof(float);      // 3.23 MB
    const size_t hb_off   = (pb_off + pb_bytes + 255) & ~(size_t)255;
    const size_t wb_off   = hb_off + (size_t)nH * 2;
    const size_t lb_off   = wb_off + (size_t)nWp * 2;                // ~115 MiB
    const size_t lb_bytes = (size_t)NROWS * VPAD * 2;                // 413 MB
    const size_t need_lb   = lb_off + lb_bytes;                      // ~528 MiB
    const size_t need_full = lb_off;                                 // ~115 MiB

    if (ws_size >= need_full) {
        __bf16* Hb = (__bf16*)((char*)d_ws + hb_off);
        __bf16* Wb = (__bf16*)((char*)d_ws + wb_off);
        float*  pb = (float*)((char*)d_ws + pb_off);
        cvt_bf16<<<(int)(nH / 8 / 256), 256, 0, stream>>>(H, Hb, nH, nH);
        cvt_bf16<<<(int)((nWp / 8 + 255) / 256), 256, 0, stream>>>(W, Wb, nW, nWp);
        if (ws_size >= need_lb) {
            __bf16* Lb = (__bf16*)((char*)d_ws + lb_off);
            gemm_fused<true><<<dim3(NWG), 512, 0, stream>>>(Hb, Wb, C, Lb, pb);
            lse_reduce<<<dim3(NROWS / 64), 256, 0, stream>>>(pb, lse);
            expand_sub<<<dim3(NROWS * 2), 256, 0, stream>>>(Lb, lse, C);
        } else {
            gemm_fused<false><<<dim3(NWG), 512, 0, stream>>>(Hb, Wb, C, (__bf16*)nullptr, pb);
            lse_reduce<<<dim3(NROWS / 64), 256, 0, stream>>>(pb, lse);
            sub_lse<<<dim3(NROWS), 256, 0, stream>>>(C, lse);
        }
    } else {
        dim3 ggrid(NROWS / FBM, (VOCAB + FBM - 1) / FBM);
        gemm_logits<<<ggrid, 256, 0, stream>>>(H, W, C);
        row_lse<<<dim3(NROWS), 256, 0, stream>>>(C, lse);
        sub_lse<<<dim3(NROWS), 256, 0, stream>>>(C, lse);
    }
}

// Round 14
// 795.514 us; speedup vs baseline: 1.0348x; 1.0348x over previous
//
#include <hip/hip_runtime.h>
#include <hip/hip_bf16.h>
#include <math.h>

#define VOCAB 50257
#define VPAD  50432          // VOCAB padded to multiple of 256
#define EMB   1024
#define NROWS 4096

#define BM 256
#define BN 256
#define BK 64
#define NKT (EMB / BK)       // 16
#define NMT (NROWS / BM)     // 16
#define NT  (VPAD / BN)      // 197
#define NWG (NMT * NT)       // 3152 (divisible by 8)

typedef __attribute__((ext_vector_type(4))) float  f32x4;
typedef __attribute__((ext_vector_type(4), aligned(4))) float f32x4u;
typedef __attribute__((ext_vector_type(4))) __bf16 bf16x4;
typedef __attribute__((ext_vector_type(8))) __bf16 bf16x8;

#define FENCE asm volatile("" ::: "memory")
#define BARRIER do { FENCE; __builtin_amdgcn_s_barrier(); FENCE; } while (0)

// ---------------------------------------------------------------------------
// fp32 -> bf16 convert (pads tail with zeros). n_src, n_dst multiples of 8.
// ---------------------------------------------------------------------------
__global__ __launch_bounds__(256)
void cvt_bf16(const float* __restrict__ src, __bf16* __restrict__ dst,
              long n_src, long n_dst) {
    long i = ((long)blockIdx.x * 256 + threadIdx.x) * 8;
    if (i >= n_dst) return;
    bf16x8 o;
    if (i < n_src) {
        f32x4 a = *(const f32x4*)(src + i);
        f32x4 b = *(const f32x4*)(src + i + 4);
        #pragma unroll
        for (int e = 0; e < 4; ++e) {
            o[e]     = (__bf16)a[e];
            o[4 + e] = (__bf16)b[e];
        }
    } else {
        #pragma unroll
        for (int e = 0; e < 8; ++e) o[e] = (__bf16)0.0f;
    }
    *(bf16x8*)(dst + i) = o;
}

// ---------------------------------------------------------------------------
// 256x256-tile bf16 GEMM (R5/R12 schedule: 4-phase fine interleave, 2 LDS
// buffers, counted vmcnt(2), 2 barriers/tile, source-order pipelined reads).
// Fused sum-exp epilogue; Lb stores first, exp/reduce drains under them.
// LB_OUT=1: bf16 logits -> Lb[row][VPAD]; LB_OUT=0: f32 -> C (fallback).
// ---------------------------------------------------------------------------
template <bool LB_OUT>
__global__ __launch_bounds__(512, 2)
void gemm_fused(const __bf16* __restrict__ A, const __bf16* __restrict__ B,
                float* __restrict__ C, __bf16* __restrict__ Lb,
                float* __restrict__ pbuf) {
    __shared__ alignas(16) __bf16 S[65536];   // 128 KiB

    const int tid  = threadIdx.x;
    const int lane = tid & 63;
    const int wave = tid >> 6;
    const int wm   = (wave >> 2) * 128;       // 2 M-halves
    const int wn   = (wave & 3) * 64;         // 4 N-quarters
    const int frow = lane & 15;
    const int hi   = lane >> 4;

    // bijective XCD swizzle: NWG = 3152, 3152/8 = 394
    const int b  = blockIdx.x;
    const int lg = (b & 7) * (NWG / 8) + (b >> 3);
    const int mt = lg & (NMT - 1);            // m-fastest: 16 blocks share W panel
    const int nt = lg >> 4;
    const int mtB = mt * BM, ntB = nt * BN;

    const int r0 = tid >> 3;
    const int ls = (tid & 7) ^ (r0 & 7);
    const __bf16* gA = A + (size_t)(mtB + r0) * EMB + ls * 8;
    const __bf16* gB = B + (size_t)(ntB + r0) * EMB + ls * 8;

    f32x4 acc[8][4];
    const f32x4 vzero = {0.f, 0.f, 0.f, 0.f};
    #pragma unroll
    for (int m = 0; m < 8; ++m)
        #pragma unroll
        for (int n = 0; n < 4; ++n) acc[m][n] = vzero;

    // unit u: 0 = B rows 0-127, 1 = B rows 128-255, 2 = A half0, 3 = A half1
#define STAGE_UNIT(bc, kt, u) do {                                            \
        const __bf16* g_ = ((u) < 2 ? gB : gA) + ((size_t)(((u)&1) * 128) * EMB + (kt) * BK); \
        __bf16* d_ = &S[(bc) * 32768 + ((u) < 2 ? 16384 : 0) + ((u)&1) * 8192 + wave * 512]; \
        __builtin_amdgcn_global_load_lds(                                     \
            (const __attribute__((address_space(1))) void*)g_,               \
            (__attribute__((address_space(3))) void*)d_, 16, 0, 0);          \
        __builtin_amdgcn_global_load_lds(                                     \
            (const __attribute__((address_space(1))) void*)(g_ + (size_t)64 * EMB), \
            (__attribute__((address_space(3))) void*)(d_ + 4096), 16, 0, 0); \
    } while (0)

#define LDA_TO(dst, c, mh, ks) { _Pragma("unroll")                            \
    for (int i_ = 0; i_ < 4; ++i_) {                                          \
        const int row_ = wm + ((mh) * 4 + i_) * 16 + frow;                    \
        dst[i_] = *(const bf16x8*)&S[(c) * 32768 + row_ * 64 + ((((ks) * 4 + hi)) ^ (row_ & 7)) * 8]; } }

#define LDB_TO(dst, c, ks) { _Pragma("unroll")                                \
    for (int n_ = 0; n_ < 4; ++n_) {                                          \
        const int row_ = wn + n_ * 16 + frow;                                 \
        dst[n_] = *(const bf16x8*)&S[(c) * 32768 + 16384 + row_ * 64 + ((((ks) * 4 + hi)) ^ (row_ & 7)) * 8]; } }

#define MFMA16(mh, AF, BF)                                                    \
    __builtin_amdgcn_s_setprio(1);                                            \
    _Pragma("unroll") for (int i_ = 0; i_ < 4; ++i_)                          \
        _Pragma("unroll") for (int n_ = 0; n_ < 4; ++n_)                      \
            acc[(mh) * 4 + i_][n_] = __builtin_amdgcn_mfma_f32_16x16x32_bf16( \
                AF[i_], BF[n_], acc[(mh) * 4 + i_][n_], 0, 0, 0);             \
    __builtin_amdgcn_s_setprio(0);

    bf16x8 afA[4], afB[4], bfrA[4], bfrB[4];

    // prologue: stage tile 0 into buf 0
    #pragma unroll
    for (int u = 0; u < 4; ++u) STAGE_UNIT(0, 0, u);

    int cur = 0;
    for (int t = 0; t < NKT; ++t) {
        const int c = cur;
        const bool pf = (t + 1 < NKT);
        if (pf) {
            STAGE_UNIT(c ^ 1, t + 1, 0);
            asm volatile("s_waitcnt vmcnt(2)" ::: "memory");  // tile t landed
        } else {
            asm volatile("s_waitcnt vmcnt(0)" ::: "memory");
        }
        BARRIER;
        // ---- pipelined 4-phase compute: reads issued one cluster ahead ----
        LDB_TO(bfrA, c, 0);
        LDA_TO(afA, c, 0, 0);
        LDA_TO(afB, c, 1, 0);            // phase-1 fragments in flight
        MFMA16(0, afA, bfrA);
        if (pf) STAGE_UNIT(c ^ 1, t + 1, 1);
        LDB_TO(bfrB, c, 1);              // phase-2/3 fragments in flight
        LDA_TO(afA, c, 0, 1);
        MFMA16(1, afB, bfrA);
        if (pf) STAGE_UNIT(c ^ 1, t + 1, 2);
        LDA_TO(afB, c, 1, 1);            // phase-3 fragments in flight
        MFMA16(0, afA, bfrB);
        if (pf) STAGE_UNIT(c ^ 1, t + 1, 3);
        MFMA16(1, afB, bfrB);
        BARRIER;                          // all waves done reading buf c
        cur ^= 1;
    }
#undef STAGE_UNIT

    // ---------------- fused epilogue (stores first, sums under them) ------
    __syncthreads();                      // staging LDS reusable
    const bool edge = (ntB + BN > VOCAB); // only last nt tile

    if (LB_OUT) {
        #pragma unroll
        for (int m = 0; m < 8; ++m) {
            const size_t rbase = (size_t)(mtB + wm + m * 16 + hi * 4) * VPAD;
            #pragma unroll
            for (int n = 0; n < 4; ++n) {
                const size_t col = ntB + wn + n * 16 + frow;
                #pragma unroll
                for (int r = 0; r < 4; ++r)
                    Lb[rbase + (size_t)r * VPAD + col] = (__bf16)acc[m][n][r];
            }
        }
    } else {
        #pragma unroll
        for (int m = 0; m < 8; ++m) {
            const size_t rbase = (size_t)(mtB + wm + m * 16 + hi * 4) * VOCAB;
            #pragma unroll
            for (int n = 0; n < 4; ++n) {
                const int col = ntB + wn + n * 16 + frow;
                if (!edge || col < VOCAB) {
                    #pragma unroll
                    for (int r = 0; r < 4; ++r)
                        C[rbase + (size_t)r * VOCAB + col] = acc[m][n][r];
                }
            }
        }
    }

    // per-lane exp-sums -> LDS transpose buffer [256 rows][68] f32 (68 KB);
    // these VALU/LDS ops drain while the stores above are in flight
    float* ldsP = (float*)&S[0];
    const int lcid = (wave & 3) * 16 + frow;   // 0..63 column-group id
    #pragma unroll
    for (int m = 0; m < 8; ++m) {
        #pragma unroll
        for (int r = 0; r < 4; ++r) {
            float s = 0.0f;
            #pragma unroll
            for (int n = 0; n < 4; ++n) {
                if (!edge || (ntB + wn + n * 16 + frow) < VOCAB)
                    s += __expf(acc[m][n][r]);
            }
            ldsP[(wm + m * 16 + hi * 4 + r) * 68 + lcid] = s;
        }
    }
    __syncthreads();

    // reduce 64 partials per row -> pbuf[nt][global row]
    {
        const int rl = tid >> 1, hf = tid & 1;
        const float* q = ldsP + rl * 68 + hf * 32;
        float s = 0.0f;
        #pragma unroll
        for (int k = 0; k < 8; ++k) {
            f32x4 v = *(const f32x4*)(q + k * 4);
            s += v[0] + v[1] + v[2] + v[3];
        }
        s += __shfl_xor(s, 1);
        if (hf == 0) pbuf[(size_t)nt * NROWS + mtB + rl] = s;
    }
}

// ---------------------------------------------------------------------------
// reduce NT per-tile sumexp partials -> lse[row]; 64 rows per block
// ---------------------------------------------------------------------------
__global__ __launch_bounds__(256)
void lse_reduce(const float* __restrict__ pbuf, float* __restrict__ lse) {
    __shared__ float sl[4][64];
    const int r0 = blockIdx.x * 64;
    const int l  = threadIdx.x & 63;
    const int w  = threadIdx.x >> 6;
    float s = 0.0f;
    for (int t = w; t < NT; t += 4)
        s += pbuf[(size_t)t * NROWS + r0 + l];
    sl[w][l] = s;
    __syncthreads();
    if (threadIdx.x < 64)
        lse[r0 + l] = __logf(sl[0][l] + sl[1][l] + sl[2][l] + sl[3][l]);
}

// ---------------------------------------------------------------------------
// C[row][col] = (float)Lb[row][col] - lse[row]; 4 blocks per row (quarters),
// nontemporal load/store (read-once / write-once data).
// ---------------------------------------------------------------------------
__global__ __launch_bounds__(256)
void expand_sub(const __bf16* __restrict__ Lb, const float* __restrict__ lse,
                float* __restrict__ C) {
    const int row = blockIdx.x >> 2;
    const int q   = blockIdx.x & 3;
    const float s = lse[row];
    const __bf16* src = Lb + (size_t)row * VPAD;
    float* dst = C + (size_t)row * VOCAB;
    // 50257 = 8*6282 + 1; quarters of 1571 chunks (last quarter 1569 + tail)
    const int i0 = q * 1571;
    const int i1 = (q == 3) ? 6282 : i0 + 1571;
    for (int i = i0 + threadIdx.x; i < i1; i += 256) {
        bf16x8 v = __builtin_nontemporal_load((const bf16x8*)(src + i * 8));
        f32x4u a, b2;
        a[0] = (float)v[0] - s; a[1] = (float)v[1] - s;
        a[2] = (float)v[2] - s; a[3] = (float)v[3] - s;
        b2[0] = (float)v[4] - s; b2[1] = (float)v[5] - s;
        b2[2] = (float)v[6] - s; b2[3] = (float)v[7] - s;
        __builtin_nontemporal_store(a,  (f32x4u*)(dst + i * 8));
        __builtin_nontemporal_store(b2, (f32x4u*)(dst + i * 8 + 4));
    }
    if (q == 3 && threadIdx.x == 0)
        dst[50256] = (float)src[50256] - s;
}

// ---------------------------------------------------------------------------
// out[row][col] -= lse[row]; fallback when Lb doesn't fit
// ---------------------------------------------------------------------------
__global__ __launch_bounds__(256)
void sub_lse(float* __restrict__ C, const float* __restrict__ lse) {
    const int row = blockIdx.x;
    const float s = lse[row];
    float* p = C + (size_t)row * VOCAB;
    for (int i = threadIdx.x; i < 12564; i += 256) {
        f32x4u v = *(const f32x4u*)(p + 4 * i);
        v[0] -= s; v[1] -= s; v[2] -= s; v[3] -= s;
        *(f32x4u*)(p + 4 * i) = v;
    }
    if (threadIdx.x == 0) p[50256] -= s;
}

// ---------------------------------------------------------------------------
// fallback fp32-input GEMM (128x128, R1 structure) if ws too small
// ---------------------------------------------------------------------------
#define FBM 128
#define FBK 32
__device__ __forceinline__ int swz_idx(int row, int col) {
    int slot = (col >> 3) ^ ((row >> 1) & 3);
    return row * FBK + slot * 8 + (col & 7);
}

__global__ __launch_bounds__(256, 2)
void gemm_logits(const float* __restrict__ H, const float* __restrict__ W,
                 float* __restrict__ C) {
    __shared__ __bf16 ldsA[FBM * FBK];
    __shared__ __bf16 ldsB[FBM * FBK];

    const int tid  = threadIdx.x;
    const int lane = tid & 63;
    const int wave = tid >> 6;
    const int wm = (wave >> 1) * 64;
    const int wn = (wave & 1) * 64;
    const int mt = blockIdx.x;
    const int nt = blockIdx.y;
    const int srow = tid >> 1;
    const int scol = (tid & 1) * 16;
    const int brow_g = nt * FBM + srow;
    const bool bvalid = brow_g < VOCAB;
    const float* aptr = H + (size_t)(mt * FBM + srow) * EMB + scol;
    const float* bptr = W + (size_t)(bvalid ? brow_g : 0) * EMB + scol;

    f32x4 areg[4], breg[4];
    #pragma unroll
    for (int q = 0; q < 4; ++q) {
        areg[q] = *(const f32x4*)(aptr + q * 4);
        breg[q] = *(const f32x4*)(bptr + q * 4);
    }
    f32x4 acc[4][4];
    const f32x4 vzero = {0.f, 0.f, 0.f, 0.f};
    #pragma unroll
    for (int i = 0; i < 4; ++i)
        #pragma unroll
        for (int j = 0; j < 4; ++j) acc[i][j] = vzero;

    const int frow = lane & 15;
    const int kcol = (lane >> 4) * 8;

    for (int kt = 0; kt < EMB / FBK; ++kt) {
        __syncthreads();
        #pragma unroll
        for (int q = 0; q < 4; ++q) {
            const int col = scol + q * 4;
            bf16x4 av, bv;
            #pragma unroll
            for (int e = 0; e < 4; ++e) {
                av[e] = (__bf16)areg[q][e];
                bv[e] = bvalid ? (__bf16)breg[q][e] : (__bf16)0.0f;
            }
            *(bf16x4*)(&ldsA[swz_idx(srow, col)]) = av;
            *(bf16x4*)(&ldsB[swz_idx(srow, col)]) = bv;
        }
        __syncthreads();
        if (kt + 1 < EMB / FBK) {
            const int ko = (kt + 1) * FBK;
            #pragma unroll
            for (int q = 0; q < 4; ++q) {
                areg[q] = *(const f32x4*)(aptr + ko + q * 4);
                breg[q] = *(const f32x4*)(bptr + ko + q * 4);
            }
        }
        bf16x8 af[4], bfr[4];
        #pragma unroll
        for (int i = 0; i < 4; ++i) {
            af[i]  = *(const bf16x8*)(&ldsA[swz_idx(wm + i * 16 + frow, kcol)]);
            bfr[i] = *(const bf16x8*)(&ldsB[swz_idx(wn + i * 16 + frow, kcol)]);
        }
        #pragma unroll
        for (int i = 0; i < 4; ++i)
            #pragma unroll
            for (int j = 0; j < 4; ++j)
                acc[i][j] = __builtin_amdgcn_mfma_f32_16x16x32_bf16(
                    af[i], bfr[j], acc[i][j], 0, 0, 0);
    }

    const int crow = mt * FBM + wm + (lane >> 4) * 4;
    const int ccol = nt * FBM + wn + (lane & 15);
    #pragma unroll
    for (int i = 0; i < 4; ++i) {
        #pragma unroll
        for (int j = 0; j < 4; ++j) {
            const int col = ccol + j * 16;
            if (col < VOCAB) {
                #pragma unroll
                for (int r = 0; r < 4; ++r)
                    C[(size_t)(crow + i * 16 + r) * VOCAB + col] = acc[i][j][r];
            }
        }
    }
}

// ---------------------------------------------------------------------------
// fallback full row LSE
// ---------------------------------------------------------------------------
__global__ __launch_bounds__(256)
void row_lse(const float* __restrict__ C, float* __restrict__ lse) {
    const int row = blockIdx.x;
    const float* p = C + (size_t)row * VOCAB;

    float m = -INFINITY, l = 0.0f;
    for (int i = threadIdx.x; i < 12564; i += 256) {
        f32x4u v = *(const f32x4u*)(p + 4 * i);
        #pragma unroll
        for (int e = 0; e < 4; ++e) {
            const float x  = v[e];
            const float mn = fmaxf(m, x);
            l = l * __expf(m - mn) + __expf(x - mn);
            m = mn;
        }
    }
    if (threadIdx.x == 0) {
        const float x  = p[50256];
        const float mn = fmaxf(m, x);
        l = l * __expf(m - mn) + __expf(x - mn);
        m = mn;
    }
    #pragma unroll
    for (int off = 1; off < 64; off <<= 1) {
        const float mo = __shfl_xor(m, off);
        const float lo = __shfl_xor(l, off);
        const float mn = fmaxf(m, mo);
        l = l * __expf(m - mn) + lo * __expf(mo - mn);
        m = mn;
    }
    __shared__ float sm[4], sl[4];
    if ((threadIdx.x & 63) == 0) { sm[threadIdx.x >> 6] = m; sl[threadIdx.x >> 6] = l; }
    __syncthreads();
    if (threadIdx.x == 0) {
        m = sm[0]; l = sl[0];
        #pragma unroll
        for (int w = 1; w < 4; ++w) {
            const float mn = fmaxf(m, sm[w]);
            l = l * __expf(m - mn) + sl[w] * __expf(sm[w] - mn);
            m = mn;
        }
        lse[row] = m + __logf(l);
    }
}

// ---------------------------------------------------------------------------
extern "C" void kernel_launch(void* const* d_in, const int* in_sizes, int n_in,
                              void* d_out, int out_size, void* d_ws, size_t ws_size,
                              hipStream_t stream) {
    const float* H = (const float*)d_in[0];   // [4096][1024]
    const float* W = (const float*)d_in[1];   // [50257][1024]
    float* C   = (float*)d_out;               // [4096][50257]
    float* lse = (float*)d_ws;                // 4096 floats @ offset 0

    const long nH  = (long)NROWS * EMB;       // 4,194,304
    const long nW  = (long)VOCAB * EMB;       // 51,463,168
    const long nWp = (long)VPAD * EMB;        // 51,642,368

    // layout: lse | pbuf | Hb | Wb | Lb
    const size_t pb_off   = 16384;
    const size_t pb_bytes = (size_t)NT * NROWS * sizeof(float);      // 3.23 MB
    const size_t hb_off   = (pb_off + pb_bytes + 255) & ~(size_t)255;
    const size_t wb_off   = hb_off + (size_t)nH * 2;
    const size_t lb_off   = wb_off + (size_t)nWp * 2;                // ~115 MiB
    const size_t lb_bytes = (size_t)NROWS * VPAD * 2;                // 413 MB
    const size_t need_lb   = lb_off + lb_bytes;                      // ~528 MiB
    const size_t need_full = lb_off;                                 // ~115 MiB

    if (ws_size >= need_full) {
        __bf16* Hb = (__bf16*)((char*)d_ws + hb_off);
        __bf16* Wb = (__bf16*)((char*)d_ws + wb_off);
        float*  pb = (float*)((char*)d_ws + pb_off);
        cvt_bf16<<<(int)(nH / 8 / 256), 256, 0, stream>>>(H, Hb, nH, nH);
        cvt_bf16<<<(int)((nWp / 8 + 255) / 256), 256, 0, stream>>>(W, Wb, nW, nWp);
        if (ws_size >= need_lb) {
            __bf16* Lb = (__bf16*)((char*)d_ws + lb_off);
            gemm_fused<true><<<dim3(NWG), 512, 0, stream>>>(Hb, Wb, C, Lb, pb);
            lse_reduce<<<dim3(NROWS / 64), 256, 0, stream>>>(pb, lse);
            expand_sub<<<dim3(NROWS * 4), 256, 0, stream>>>(Lb, lse, C);
        } else {
            gemm_fused<false><<<dim3(NWG), 512, 0, stream>>>(Hb, Wb, C, (__bf16*)nullptr, pb);
            lse_reduce<<<dim3(NROWS / 64), 256, 0, stream>>>(pb, lse);
            sub_lse<<<dim3(NROWS), 256, 0, stream>>>(C, lse);
        }
    } else {
        dim3 ggrid(NROWS / FBM, (VOCAB + FBM - 1) / FBM);
        gemm_logits<<<ggrid, 256, 0, stream>>>(H, W, C);
        row_lse<<<dim3(NROWS), 256, 0, stream>>>(C, lse);
        sub_lse<<<dim3(NROWS), 256, 0, stream>>>(C, lse);
    }
}

// Round 15
// 787.042 us; speedup vs baseline: 1.0459x; 1.0108x over previous
//
#include <hip/hip_runtime.h>
#include <hip/hip_bf16.h>
#include <math.h>

#define VOCAB 50257
#define VPAD  50432          // VOCAB padded to multiple of 256
#define EMB   1024
#define NROWS 4096

#define BM 256
#define BN 256
#define BK 64
#define NKT (EMB / BK)       // 16
#define NMT (NROWS / BM)     // 16
#define NT  (VPAD / BN)      // 197
#define NWG (NMT * NT)       // 3152 (divisible by 8)

typedef __attribute__((ext_vector_type(4))) float  f32x4;
typedef __attribute__((ext_vector_type(4), aligned(4))) float f32x4u;
typedef __attribute__((ext_vector_type(4))) __bf16 bf16x4;
typedef __attribute__((ext_vector_type(8))) __bf16 bf16x8;

#define FENCE asm volatile("" ::: "memory")
#define BARRIER do { FENCE; __builtin_amdgcn_s_barrier(); FENCE; } while (0)

// ---------------------------------------------------------------------------
// fp32 -> bf16 convert (pads tail with zeros). n_src, n_dst multiples of 8.
// ---------------------------------------------------------------------------
__global__ __launch_bounds__(256)
void cvt_bf16(const float* __restrict__ src, __bf16* __restrict__ dst,
              long n_src, long n_dst) {
    long i = ((long)blockIdx.x * 256 + threadIdx.x) * 8;
    if (i >= n_dst) return;
    bf16x8 o;
    if (i < n_src) {
        f32x4 a = *(const f32x4*)(src + i);
        f32x4 b = *(const f32x4*)(src + i + 4);
        #pragma unroll
        for (int e = 0; e < 4; ++e) {
            o[e]     = (__bf16)a[e];
            o[4 + e] = (__bf16)b[e];
        }
    } else {
        #pragma unroll
        for (int e = 0; e < 8; ++e) o[e] = (__bf16)0.0f;
    }
    *(bf16x8*)(dst + i) = o;
}

// ---------------------------------------------------------------------------
// 256x256-tile bf16 GEMM (R12 skeleton: 4-phase fine interleave, 2 LDS
// buffers, source-order pipelined ds_reads) with:
//  - shifted stage calendar: u0+u1 of t+1 at ph0 (vmcnt(4)), u2 ph1, u3 ph2
//  - 8mt x 2nt chunk mapping for XCD-L2 working-set reduction
//  - K-loop unrolled x2
// Fused sum-exp epilogue; Lb stores first, exp/reduce drains under them.
// LB_OUT=1: bf16 logits -> Lb[row][VPAD]; LB_OUT=0: f32 -> C (fallback).
// ---------------------------------------------------------------------------
template <bool LB_OUT>
__global__ __launch_bounds__(512, 2)
void gemm_fused(const __bf16* __restrict__ A, const __bf16* __restrict__ B,
                float* __restrict__ C, __bf16* __restrict__ Lb,
                float* __restrict__ pbuf) {
    __shared__ alignas(16) __bf16 S[65536];   // 128 KiB

    const int tid  = threadIdx.x;
    const int lane = tid & 63;
    const int wave = tid >> 6;
    const int wm   = (wave >> 2) * 128;       // 2 M-halves
    const int wn   = (wave & 3) * 64;         // 4 N-quarters
    const int frow = lane & 15;
    const int hi   = lane >> 4;

    // bijective XCD swizzle, then 8mt x 2nt chunks (keeps <=6MB hot window
    // on the 4MB XCD L2 vs 8.5MB for m-fastest columns)
    const int b  = blockIdx.x;
    const int lg = (b & 7) * (NWG / 8) + (b >> 3);
    const int q  = lg >> 4, w = lg & 15;
    int mt, nt;
    if (q == 196) { mt = w; nt = 196; }                        // last nt column
    else { mt = (q & 1) * 8 + (w & 7); nt = (q >> 1) * 2 + (w >> 3); }
    const int mtB = mt * BM, ntB = nt * BN;

    const int r0 = tid >> 3;
    const int ls = (tid & 7) ^ (r0 & 7);
    const __bf16* gA = A + (size_t)(mtB + r0) * EMB + ls * 8;
    const __bf16* gB = B + (size_t)(ntB + r0) * EMB + ls * 8;

    f32x4 acc[8][4];
    const f32x4 vzero = {0.f, 0.f, 0.f, 0.f};
    #pragma unroll
    for (int m = 0; m < 8; ++m)
        #pragma unroll
        for (int n = 0; n < 4; ++n) acc[m][n] = vzero;

    // unit u: 0 = B rows 0-127, 1 = B rows 128-255, 2 = A half0, 3 = A half1
#define STAGE_UNIT(bc, kt, u) do {                                            \
        const __bf16* g_ = ((u) < 2 ? gB : gA) + ((size_t)(((u)&1) * 128) * EMB + (kt) * BK); \
        __bf16* d_ = &S[(bc) * 32768 + ((u) < 2 ? 16384 : 0) + ((u)&1) * 8192 + wave * 512]; \
        __builtin_amdgcn_global_load_lds(                                     \
            (const __attribute__((address_space(1))) void*)g_,               \
            (__attribute__((address_space(3))) void*)d_, 16, 0, 0);          \
        __builtin_amdgcn_global_load_lds(                                     \
            (const __attribute__((address_space(1))) void*)(g_ + (size_t)64 * EMB), \
            (__attribute__((address_space(3))) void*)(d_ + 4096), 16, 0, 0); \
    } while (0)

#define LDA_TO(dst, c, mh, ks) { _Pragma("unroll")                            \
    for (int i_ = 0; i_ < 4; ++i_) {                                          \
        const int row_ = wm + ((mh) * 4 + i_) * 16 + frow;                    \
        dst[i_] = *(const bf16x8*)&S[(c) * 32768 + row_ * 64 + ((((ks) * 4 + hi)) ^ (row_ & 7)) * 8]; } }

#define LDB_TO(dst, c, ks) { _Pragma("unroll")                                \
    for (int n_ = 0; n_ < 4; ++n_) {                                          \
        const int row_ = wn + n_ * 16 + frow;                                 \
        dst[n_] = *(const bf16x8*)&S[(c) * 32768 + 16384 + row_ * 64 + ((((ks) * 4 + hi)) ^ (row_ & 7)) * 8]; } }

#define MFMA16(mh, AF, BF)                                                    \
    __builtin_amdgcn_s_setprio(1);                                            \
    _Pragma("unroll") for (int i_ = 0; i_ < 4; ++i_)                          \
        _Pragma("unroll") for (int n_ = 0; n_ < 4; ++n_)                      \
            acc[(mh) * 4 + i_][n_] = __builtin_amdgcn_mfma_f32_16x16x32_bf16( \
                AF[i_], BF[n_], acc[(mh) * 4 + i_][n_], 0, 0, 0);             \
    __builtin_amdgcn_s_setprio(0);

    bf16x8 afA[4], afB[4], bfrA[4], bfrB[4];

    // prologue: stage tile 0 into buf 0
    #pragma unroll
    for (int u = 0; u < 4; ++u) STAGE_UNIT(0, 0, u);

    #pragma unroll 2
    for (int t = 0; t < NKT; ++t) {
        const int c = t & 1;
        const bool pf = (t + 1 < NKT);
        // ---- phase 0: stage u0+u1 of t+1, wait tile t, compute (ks0,mh0) --
        if (pf) {
            STAGE_UNIT(c ^ 1, t + 1, 0);
            STAGE_UNIT(c ^ 1, t + 1, 1);
            asm volatile("s_waitcnt vmcnt(4)" ::: "memory");  // tile t landed
        } else {
            asm volatile("s_waitcnt vmcnt(0)" ::: "memory");
        }
        BARRIER;
        LDB_TO(bfrA, c, 0);
        LDA_TO(afA, c, 0, 0);
        LDA_TO(afB, c, 1, 0);            // phase-1 fragments in flight
        MFMA16(0, afA, bfrA);
        // ---- phase 1 ----
        if (pf) STAGE_UNIT(c ^ 1, t + 1, 2);
        LDB_TO(bfrB, c, 1);              // phase-2/3 fragments in flight
        LDA_TO(afA, c, 0, 1);
        MFMA16(1, afB, bfrA);
        // ---- phase 2 ----
        if (pf) STAGE_UNIT(c ^ 1, t + 1, 3);
        LDA_TO(afB, c, 1, 1);            // phase-3 fragments in flight
        MFMA16(0, afA, bfrB);
        // ---- phase 3 (no staging: u3 issued a phase earlier) ----
        MFMA16(1, afB, bfrB);
        BARRIER;                          // all waves done reading buf c
    }
#undef STAGE_UNIT

    // ---------------- fused epilogue (stores first, sums under them) ------
    __syncthreads();                      // staging LDS reusable
    const bool edge = (ntB + BN > VOCAB); // only last nt tile

    if (LB_OUT) {
        #pragma unroll
        for (int m = 0; m < 8; ++m) {
            const size_t rbase = (size_t)(mtB + wm + m * 16 + hi * 4) * VPAD;
            #pragma unroll
            for (int n = 0; n < 4; ++n) {
                const size_t col = ntB + wn + n * 16 + frow;
                #pragma unroll
                for (int r = 0; r < 4; ++r)
                    Lb[rbase + (size_t)r * VPAD + col] = (__bf16)acc[m][n][r];
            }
        }
    } else {
        #pragma unroll
        for (int m = 0; m < 8; ++m) {
            const size_t rbase = (size_t)(mtB + wm + m * 16 + hi * 4) * VOCAB;
            #pragma unroll
            for (int n = 0; n < 4; ++n) {
                const int col = ntB + wn + n * 16 + frow;
                if (!edge || col < VOCAB) {
                    #pragma unroll
                    for (int r = 0; r < 4; ++r)
                        C[rbase + (size_t)r * VOCAB + col] = acc[m][n][r];
                }
            }
        }
    }

    // per-lane exp-sums -> LDS transpose buffer [256 rows][68] f32 (68 KB);
    // these VALU/LDS ops drain while the stores above are in flight
    float* ldsP = (float*)&S[0];
    const int lcid = (wave & 3) * 16 + frow;   // 0..63 column-group id
    #pragma unroll
    for (int m = 0; m < 8; ++m) {
        #pragma unroll
        for (int r = 0; r < 4; ++r) {
            float s = 0.0f;
            #pragma unroll
            for (int n = 0; n < 4; ++n) {
                if (!edge || (ntB + wn + n * 16 + frow) < VOCAB)
                    s += __expf(acc[m][n][r]);
            }
            ldsP[(wm + m * 16 + hi * 4 + r) * 68 + lcid] = s;
        }
    }
    __syncthreads();

    // reduce 64 partials per row -> pbuf[nt][global row]
    {
        const int rl = tid >> 1, hf = tid & 1;
        const float* q2 = ldsP + rl * 68 + hf * 32;
        float s = 0.0f;
        #pragma unroll
        for (int k = 0; k < 8; ++k) {
            f32x4 v = *(const f32x4*)(q2 + k * 4);
            s += v[0] + v[1] + v[2] + v[3];
        }
        s += __shfl_xor(s, 1);
        if (hf == 0) pbuf[(size_t)nt * NROWS + mtB + rl] = s;
    }
}

// ---------------------------------------------------------------------------
// reduce NT per-tile sumexp partials -> lse[row]; 64 rows per block
// ---------------------------------------------------------------------------
__global__ __launch_bounds__(256)
void lse_reduce(const float* __restrict__ pbuf, float* __restrict__ lse) {
    __shared__ float sl[4][64];
    const int r0 = blockIdx.x * 64;
    const int l  = threadIdx.x & 63;
    const int w  = threadIdx.x >> 6;
    float s = 0.0f;
    for (int t = w; t < NT; t += 4)
        s += pbuf[(size_t)t * NROWS + r0 + l];
    sl[w][l] = s;
    __syncthreads();
    if (threadIdx.x < 64)
        lse[r0 + l] = __logf(sl[0][l] + sl[1][l] + sl[2][l] + sl[3][l]);
}

// ---------------------------------------------------------------------------
// C[row][col] = (float)Lb[row][col] - lse[row]; 4 blocks per row (quarters),
// nontemporal load/store (read-once / write-once data).
// ---------------------------------------------------------------------------
__global__ __launch_bounds__(256)
void expand_sub(const __bf16* __restrict__ Lb, const float* __restrict__ lse,
                float* __restrict__ C) {
    const int row = blockIdx.x >> 2;
    const int q   = blockIdx.x & 3;
    const float s = lse[row];
    const __bf16* src = Lb + (size_t)row * VPAD;
    float* dst = C + (size_t)row * VOCAB;
    // 50257 = 8*6282 + 1; quarters of 1571 chunks (last quarter 1569 + tail)
    const int i0 = q * 1571;
    const int i1 = (q == 3) ? 6282 : i0 + 1571;
    for (int i = i0 + threadIdx.x; i < i1; i += 256) {
        bf16x8 v = __builtin_nontemporal_load((const bf16x8*)(src + i * 8));
        f32x4u a, b2;
        a[0] = (float)v[0] - s; a[1] = (float)v[1] - s;
        a[2] = (float)v[2] - s; a[3] = (float)v[3] - s;
        b2[0] = (float)v[4] - s; b2[1] = (float)v[5] - s;
        b2[2] = (float)v[6] - s; b2[3] = (float)v[7] - s;
        __builtin_nontemporal_store(a,  (f32x4u*)(dst + i * 8));
        __builtin_nontemporal_store(b2, (f32x4u*)(dst + i * 8 + 4));
    }
    if (q == 3 && threadIdx.x == 0)
        dst[50256] = (float)src[50256] - s;
}

// ---------------------------------------------------------------------------
// out[row][col] -= lse[row]; fallback when Lb doesn't fit
// ---------------------------------------------------------------------------
__global__ __launch_bounds__(256)
void sub_lse(float* __restrict__ C, const float* __restrict__ lse) {
    const int row = blockIdx.x;
    const float s = lse[row];
    float* p = C + (size_t)row * VOCAB;
    for (int i = threadIdx.x; i < 12564; i += 256) {
        f32x4u v = *(const f32x4u*)(p + 4 * i);
        v[0] -= s; v[1] -= s; v[2] -= s; v[3] -= s;
        *(f32x4u*)(p + 4 * i) = v;
    }
    if (threadIdx.x == 0) p[50256] -= s;
}

// ---------------------------------------------------------------------------
// fallback fp32-input GEMM (128x128, R1 structure) if ws too small
// ---------------------------------------------------------------------------
#define FBM 128
#define FBK 32
__device__ __forceinline__ int swz_idx(int row, int col) {
    int slot = (col >> 3) ^ ((row >> 1) & 3);
    return row * FBK + slot * 8 + (col & 7);
}

__global__ __launch_bounds__(256, 2)
void gemm_logits(const float* __restrict__ H, const float* __restrict__ W,
                 float* __restrict__ C) {
    __shared__ __bf16 ldsA[FBM * FBK];
    __shared__ __bf16 ldsB[FBM * FBK];

    const int tid  = threadIdx.x;
    const int lane = tid & 63;
    const int wave = tid >> 6;
    const int wm = (wave >> 1) * 64;
    const int wn = (wave & 1) * 64;
    const int mt = blockIdx.x;
    const int nt = blockIdx.y;
    const int srow = tid >> 1;
    const int scol = (tid & 1) * 16;
    const int brow_g = nt * FBM + srow;
    const bool bvalid = brow_g < VOCAB;
    const float* aptr = H + (size_t)(mt * FBM + srow) * EMB + scol;
    const float* bptr = W + (size_t)(bvalid ? brow_g : 0) * EMB + scol;

    f32x4 areg[4], breg[4];
    #pragma unroll
    for (int q = 0; q < 4; ++q) {
        areg[q] = *(const f32x4*)(aptr + q * 4);
        breg[q] = *(const f32x4*)(bptr + q * 4);
    }
    f32x4 acc[4][4];
    const f32x4 vzero = {0.f, 0.f, 0.f, 0.f};
    #pragma unroll
    for (int i = 0; i < 4; ++i)
        #pragma unroll
        for (int j = 0; j < 4; ++j) acc[i][j] = vzero;

    const int frow = lane & 15;
    const int kcol = (lane >> 4) * 8;

    for (int kt = 0; kt < EMB / FBK; ++kt) {
        __syncthreads();
        #pragma unroll
        for (int q = 0; q < 4; ++q) {
            const int col = scol + q * 4;
            bf16x4 av, bv;
            #pragma unroll
            for (int e = 0; e < 4; ++e) {
                av[e] = (__bf16)areg[q][e];
                bv[e] = bvalid ? (__bf16)breg[q][e] : (__bf16)0.0f;
            }
            *(bf16x4*)(&ldsA[swz_idx(srow, col)]) = av;
            *(bf16x4*)(&ldsB[swz_idx(srow, col)]) = bv;
        }
        __syncthreads();
        if (kt + 1 < EMB / FBK) {
            const int ko = (kt + 1) * FBK;
            #pragma unroll
            for (int q = 0; q < 4; ++q) {
                areg[q] = *(const f32x4*)(aptr + ko + q * 4);
                breg[q] = *(const f32x4*)(bptr + ko + q * 4);
            }
        }
        bf16x8 af[4], bfr[4];
        #pragma unroll
        for (int i = 0; i < 4; ++i) {
            af[i]  = *(const bf16x8*)(&ldsA[swz_idx(wm + i * 16 + frow, kcol)]);
            bfr[i] = *(const bf16x8*)(&ldsB[swz_idx(wn + i * 16 + frow, kcol)]);
        }
        #pragma unroll
        for (int i = 0; i < 4; ++i)
            #pragma unroll
            for (int j = 0; j < 4; ++j)
                acc[i][j] = __builtin_amdgcn_mfma_f32_16x16x32_bf16(
                    af[i], bfr[j], acc[i][j], 0, 0, 0);
    }

    const int crow = mt * FBM + wm + (lane >> 4) * 4;
    const int ccol = nt * FBM + wn + (lane & 15);
    #pragma unroll
    for (int i = 0; i < 4; ++i) {
        #pragma unroll
        for (int j = 0; j < 4; ++j) {
            const int col = ccol + j * 16;
            if (col < VOCAB) {
                #pragma unroll
                for (int r = 0; r < 4; ++r)
                    C[(size_t)(crow + i * 16 + r) * VOCAB + col] = acc[i][j][r];
            }
        }
    }
}

// ---------------------------------------------------------------------------
// fallback full row LSE
// ---------------------------------------------------------------------------
__global__ __launch_bounds__(256)
void row_lse(const float* __restrict__ C, float* __restrict__ lse) {
    const int row = blockIdx.x;
    const float* p = C + (size_t)row * VOCAB;

    float m = -INFINITY, l = 0.0f;
    for (int i = threadIdx.x; i < 12564; i += 256) {
        f32x4u v = *(const f32x4u*)(p + 4 * i);
        #pragma unroll
        for (int e = 0; e < 4; ++e) {
            const float x  = v[e];
            const float mn = fmaxf(m, x);
            l = l * __expf(m - mn) + __expf(x - mn);
            m = mn;
        }
    }
    if (threadIdx.x == 0) {
        const float x  = p[50256];
        const float mn = fmaxf(m, x);
        l = l * __expf(m - mn) + __expf(x - mn);
        m = mn;
    }
    #pragma unroll
    for (int off = 1; off < 64; off <<= 1) {
        const float mo = __shfl_xor(m, off);
        const float lo = __shfl_xor(l, off);
        const float mn = fmaxf(m, mo);
        l = l * __expf(m - mn) + lo * __expf(mo - mn);
        m = mn;
    }
    __shared__ float sm[4], sl[4];
    if ((threadIdx.x & 63) == 0) { sm[threadIdx.x >> 6] = m; sl[threadIdx.x >> 6] = l; }
    __syncthreads();
    if (threadIdx.x == 0) {
        m = sm[0]; l = sl[0];
        #pragma unroll
        for (int w = 1; w < 4; ++w) {
            const float mn = fmaxf(m, sm[w]);
            l = l * __expf(m - mn) + sl[w] * __expf(sm[w] - mn);
            m = mn;
        }
        lse[row] = m + __logf(l);
    }
}

// ---------------------------------------------------------------------------
extern "C" void kernel_launch(void* const* d_in, const int* in_sizes, int n_in,
                              void* d_out, int out_size, void* d_ws, size_t ws_size,
                              hipStream_t stream) {
    const float* H = (const float*)d_in[0];   // [4096][1024]
    const float* W = (const float*)d_in[1];   // [50257][1024]
    float* C   = (float*)d_out;               // [4096][50257]
    float* lse = (float*)d_ws;                // 4096 floats @ offset 0

    const long nH  = (long)NROWS * EMB;       // 4,194,304
    const long nW  = (long)VOCAB * EMB;       // 51,463,168
    const long nWp = (long)VPAD * EMB;        // 51,642,368

    // layout: lse | pbuf | Hb | Wb | Lb
    const size_t pb_off   = 16384;
    const size_t pb_bytes = (size_t)NT * NROWS * sizeof(float);      // 3.23 MB
    const size_t hb_off   = (pb_off + pb_bytes + 255) & ~(size_t)255;
    const size_t wb_off   = hb_off + (size_t)nH * 2;
    const size_t lb_off   = wb_off + (size_t)nWp * 2;                // ~115 MiB
    const size_t lb_bytes = (size_t)NROWS * VPAD * 2;                // 413 MB
    const size_t need_lb   = lb_off + lb_bytes;                      // ~528 MiB
    const size_t need_full = lb_off;                                 // ~115 MiB

    if (ws_size >= need_full) {
        __bf16* Hb = (__bf16*)((char*)d_ws + hb_off);
        __bf16* Wb = (__bf16*)((char*)d_ws + wb_off);
        float*  pb = (float*)((char*)d_ws + pb_off);
        cvt_bf16<<<(int)(nH / 8 / 256), 256, 0, stream>>>(H, Hb, nH, nH);
        cvt_bf16<<<(int)((nWp / 8 + 255) / 256), 256, 0, stream>>>(W, Wb, nW, nWp);
        if (ws_size >= need_lb) {
            __bf16* Lb = (__bf16*)((char*)d_ws + lb_off);
            gemm_fused<true><<<dim3(NWG), 512, 0, stream>>>(Hb, Wb, C, Lb, pb);
            lse_reduce<<<dim3(NROWS / 64), 256, 0, stream>>>(pb, lse);
            expand_sub<<<dim3(NROWS * 4), 256, 0, stream>>>(Lb, lse, C);
        } else {
            gemm_fused<false><<<dim3(NWG), 512, 0, stream>>>(Hb, Wb, C, (__bf16*)nullptr, pb);
            lse_reduce<<<dim3(NROWS / 64), 256, 0, stream>>>(pb, lse);
            sub_lse<<<dim3(NROWS), 256, 0, stream>>>(C, lse);
        }
    } else {
        dim3 ggrid(NROWS / FBM, (VOCAB + FBM - 1) / FBM);
        gemm_logits<<<ggrid, 256, 0, stream>>>(H, W, C);
        row_lse<<<dim3(NROWS), 256, 0, stream>>>(C, lse);
        sub_lse<<<dim3(NROWS), 256, 0, stream>>>(C, lse);
    }
}